// Round 1
// baseline (334.705 us; speedup 1.0000x reference)
//
#include <hip/hip_runtime.h>
#include <hip/hip_bf16.h>

// SelfAttention: x[2,2048,1024] -> qkv -> 16-head attention -> out proj.
// Strategy: bf16 MFMA everywhere (threshold ~8 bf16-ulps allows it; softmax
// averaging attenuates bf16 input-rounding noise), fp32 accumulation.

typedef __attribute__((ext_vector_type(8))) __bf16 bf16x8;
typedef __attribute__((ext_vector_type(4))) __bf16 bf16x4;
typedef __attribute__((ext_vector_type(4))) float f32x4;

__device__ __forceinline__ void gload_lds16(const void* g, void* l) {
    __builtin_amdgcn_global_load_lds((const __attribute__((address_space(1))) void*)g,
                                     (__attribute__((address_space(3))) void*)l, 16, 0, 0);
}

// ---------------- pre-pass: f32 -> bf16 (vector x4) ----------------
__global__ __launch_bounds__(256) void k_cvt(const float* __restrict__ in,
                                             __bf16* __restrict__ out, int n4) {
    int i = blockIdx.x * 256 + threadIdx.x;
    if (i >= n4) return;
    float4 v = ((const float4*)in)[i];
    bf16x4 r = {(__bf16)v.x, (__bf16)v.y, (__bf16)v.z, (__bf16)v.w};
    ((bf16x4*)out)[i] = r;
}

// ---------------- pre-pass: W [K][N] f32 -> Wt [N][K] bf16 ----------------
__global__ __launch_bounds__(256) void k_transpose(const float* __restrict__ W,
                                                   __bf16* __restrict__ Wt, int K, int N) {
    __shared__ float t[32][33];
    int n0 = blockIdx.x * 32, k0 = blockIdx.y * 32;
    int tx = threadIdx.x & 31, ty = threadIdx.x >> 5;
    for (int j = ty; j < 32; j += 8) t[j][tx] = W[(size_t)(k0 + j) * N + n0 + tx];
    __syncthreads();
    for (int j = ty; j < 32; j += 8)
        Wt[(size_t)(n0 + j) * K + k0 + tx] = (__bf16)t[tx][j];
}

// ---------------- GEMM: C[M][N] = A[M][K] * Bt[N][K]^T + bias ----------------
// 128x128 tile, BK=32, 4 waves each 64x64 (4x4 16x16x32 mfma). m97 structure.
template <int OUTMODE>  // 0: bf16 out, 1: f32 out
__global__ __launch_bounds__(256) void k_gemm_bt(const __bf16* __restrict__ A,
                                                 const __bf16* __restrict__ Bt,
                                                 const float* __restrict__ bias,
                                                 void* __restrict__ Cv, int M, int N, int K) {
    __shared__ __bf16 As[128 * 32];
    __shared__ __bf16 Bs[128 * 32];
    const int tn = blockIdx.x * 128, tm = blockIdx.y * 128;
    const int tid = threadIdx.x, lane = tid & 63, wid = tid >> 6;
    const int wr = wid >> 1, wc = wid & 1;
    const int llo = lane & 15, lhi = lane >> 4;
    f32x4 acc[4][4] = {};
    for (int kk = 0; kk < K; kk += 32) {
        __syncthreads();
#pragma unroll
        for (int j = 0; j < 2; ++j) {
            const int elem = wid * 1024 + j * 512 + lane * 8;
            const int row = elem >> 5, col = elem & 31;
            gload_lds16(A + (size_t)(tm + row) * K + kk + col, (char*)As + 2 * (wid * 1024 + j * 512));
            gload_lds16(Bt + (size_t)(tn + row) * K + kk + col, (char*)Bs + 2 * (wid * 1024 + j * 512));
        }
        __syncthreads();
        bf16x8 af[4], bfr[4];
#pragma unroll
        for (int m = 0; m < 4; ++m)
            af[m] = *(const bf16x8*)(As + (64 * wr + 16 * m + llo) * 32 + 8 * lhi);
#pragma unroll
        for (int n = 0; n < 4; ++n)
            bfr[n] = *(const bf16x8*)(Bs + (64 * wc + 16 * n + llo) * 32 + 8 * lhi);
#pragma unroll
        for (int m = 0; m < 4; ++m)
#pragma unroll
            for (int n = 0; n < 4; ++n)
                acc[m][n] = __builtin_amdgcn_mfma_f32_16x16x32_bf16(af[m], bfr[n], acc[m][n], 0, 0, 0);
    }
    const int row0 = tm + 64 * wr + 4 * lhi, col0 = tn + 64 * wc + llo;
#pragma unroll
    for (int n = 0; n < 4; ++n) {
        const int col = col0 + 16 * n;
        const float bv = bias[col];
#pragma unroll
        for (int m = 0; m < 4; ++m)
#pragma unroll
            for (int r = 0; r < 4; ++r) {
                const int row = row0 + 16 * m + r;
                const float val = acc[m][n][r] + bv;
                if (OUTMODE == 0) ((__bf16*)Cv)[(size_t)row * N + col] = (__bf16)val;
                else ((float*)Cv)[(size_t)row * N + col] = val;
            }
    }
}

// ---------------- flash attention ----------------
// qkv: [4096][3072] bf16 (cols: q=h*64.., k=1024+h*64.., v=2048+h*64..)
// out: [4096][1024] bf16. grid (16 qtiles, 32 bh), 256 threads (4 waves).
// Each wave: 32 q-rows. KT=64 keys/iter.
__global__ __launch_bounds__(256) void k_attn(const __bf16* __restrict__ qkv,
                                              __bf16* __restrict__ out) {
    constexpr int LDK = 72;  // padded stride (144B, 16B-aligned, 2-way-free reads)
    __shared__ __bf16 Kl[64 * LDK];
    __shared__ __bf16 Vt[64 * LDK];   // V transposed: [dk][key]
    __shared__ __bf16 Pl[128 * LDK];  // Q staging, then per-wave P tiles
    const int qt = blockIdx.x, bh = blockIdx.y;
    const int b = bh >> 4, h = bh & 15;
    const size_t rowbase = (size_t)b * 2048;
    const int tid = threadIdx.x, lane = tid & 63, wid = tid >> 6;
    const int llo = lane & 15, lhi = lane >> 4;

    // stage Q tile [128][64] into Pl, pull fragments into registers
#pragma unroll
    for (int it = 0; it < 4; ++it) {
        const int idx = it * 256 + tid;
        const int r = idx >> 3, dk0 = (idx & 7) * 8;
        bf16x8 v = *(const bf16x8*)(qkv + (rowbase + (size_t)qt * 128 + r) * 3072 + h * 64 + dk0);
        *(bf16x8*)(Pl + r * LDK + dk0) = v;
    }
    __syncthreads();
    bf16x8 qf[2][2];
#pragma unroll
    for (int m = 0; m < 2; ++m)
#pragma unroll
        for (int ks = 0; ks < 2; ++ks)
            qf[m][ks] = *(const bf16x8*)(Pl + (32 * wid + 16 * m + llo) * LDK + 32 * ks + 8 * lhi);
    __syncthreads();

    float mrun[2][4], lrun[2][4];
    f32x4 acco[2][4] = {};
#pragma unroll
    for (int m = 0; m < 2; ++m)
#pragma unroll
        for (int r = 0; r < 4; ++r) { mrun[m][r] = -1e30f; lrun[m][r] = 0.f; }

    __bf16* Pw = Pl + wid * 32 * LDK;
    constexpr float SC = 0.18033688011112042f;  // (1/8) * log2(e)

    for (int kt = 0; kt < 32; ++kt) {
        __syncthreads();
        // stage K [key][dk] and V transposed [dk][key]
#pragma unroll
        for (int it = 0; it < 2; ++it) {
            const int idx = it * 256 + tid;
            const int key = idx >> 3, dk0 = (idx & 7) * 8;
            const size_t grow = (rowbase + (size_t)kt * 64 + key) * 3072 + h * 64;
            bf16x8 kv = *(const bf16x8*)(qkv + grow + 1024 + dk0);
            *(bf16x8*)(Kl + key * LDK + dk0) = kv;
            bf16x8 vv = *(const bf16x8*)(qkv + grow + 2048 + dk0);
#pragma unroll
            for (int j = 0; j < 8; ++j) Vt[(dk0 + j) * LDK + key] = vv[j];
        }
        __syncthreads();
        // S = Q K^T (raw scores; 1/8 folded into exp2 scale)
        f32x4 sf[2][4] = {};
#pragma unroll
        for (int ks = 0; ks < 2; ++ks)
#pragma unroll
            for (int n = 0; n < 4; ++n) {
                const bf16x8 bfr = *(const bf16x8*)(Kl + (n * 16 + llo) * LDK + 32 * ks + 8 * lhi);
#pragma unroll
                for (int m = 0; m < 2; ++m)
                    sf[m][n] = __builtin_amdgcn_mfma_f32_16x16x32_bf16(qf[m][ks], bfr, sf[m][n], 0, 0, 0);
            }
        // online softmax (rows replicated across 16-lane groups)
#pragma unroll
        for (int m = 0; m < 2; ++m)
#pragma unroll
            for (int r = 0; r < 4; ++r) {
                float t = fmaxf(fmaxf(sf[m][0][r], sf[m][1][r]), fmaxf(sf[m][2][r], sf[m][3][r]));
                t = fmaxf(t, __shfl_xor(t, 1)); t = fmaxf(t, __shfl_xor(t, 2));
                t = fmaxf(t, __shfl_xor(t, 4)); t = fmaxf(t, __shfl_xor(t, 8));
                const float newm = fmaxf(mrun[m][r], t);
                const float corr = exp2f((mrun[m][r] - newm) * SC);
                mrun[m][r] = newm;
                float rs = 0.f;
#pragma unroll
                for (int n = 0; n < 4; ++n) {
                    const float p = exp2f((sf[m][n][r] - newm) * SC);
                    sf[m][n][r] = p;
                    rs += p;
                }
                rs += __shfl_xor(rs, 1); rs += __shfl_xor(rs, 2);
                rs += __shfl_xor(rs, 4); rs += __shfl_xor(rs, 8);
                lrun[m][r] = lrun[m][r] * corr + rs;
#pragma unroll
                for (int n = 0; n < 4; ++n) acco[m][n][r] *= corr;
            }
        // P -> wave-private LDS (DS ops in-order per wave; no barrier needed)
#pragma unroll
        for (int m = 0; m < 2; ++m)
#pragma unroll
            for (int n = 0; n < 4; ++n)
#pragma unroll
                for (int r = 0; r < 4; ++r)
                    Pw[(16 * m + 4 * lhi + r) * LDK + n * 16 + llo] = (__bf16)sf[m][n][r];
        // O += P @ V
#pragma unroll
        for (int ks = 0; ks < 2; ++ks) {
            bf16x8 pa[2];
#pragma unroll
            for (int m = 0; m < 2; ++m)
                pa[m] = *(const bf16x8*)(Pw + (16 * m + llo) * LDK + 32 * ks + 8 * lhi);
#pragma unroll
            for (int n = 0; n < 4; ++n) {
                const bf16x8 bfr = *(const bf16x8*)(Vt + (n * 16 + llo) * LDK + 32 * ks + 8 * lhi);
#pragma unroll
                for (int m = 0; m < 2; ++m)
                    acco[m][n] = __builtin_amdgcn_mfma_f32_16x16x32_bf16(pa[m], bfr, acco[m][n], 0, 0, 0);
            }
        }
    }
    // epilogue: normalize, write [4096][1024] bf16
#pragma unroll
    for (int m = 0; m < 2; ++m)
#pragma unroll
        for (int r = 0; r < 4; ++r) {
            const float inv = 1.f / lrun[m][r];
            const size_t row = rowbase + (size_t)qt * 128 + 32 * wid + 16 * m + 4 * lhi + r;
#pragma unroll
            for (int n = 0; n < 4; ++n)
                out[row * 1024 + h * 64 + n * 16 + llo] = (__bf16)(acco[m][n][r] * inv);
        }
}

extern "C" void kernel_launch(void* const* d_in, const int* in_sizes, int n_in,
                              void* d_out, int out_size, void* d_ws, size_t ws_size,
                              hipStream_t stream) {
    const float* x    = (const float*)d_in[0];
    const float* Wqkv = (const float*)d_in[1];
    const float* bqkv = (const float*)d_in[2];
    const float* Wout = (const float*)d_in[3];
    const float* bout = (const float*)d_in[4];
    float* outp = (float*)d_out;
    char* ws = (char*)d_ws;
    // workspace layout (bytes): xb 8MB | Wqkv_t 6MB | Wout_t 2MB | qkv 24MB | attn 8MB
    __bf16* xb     = (__bf16*)(ws);
    __bf16* Wqkv_t = (__bf16*)(ws + (size_t)(8u << 20));
    __bf16* Wout_t = (__bf16*)(ws + (size_t)(14u << 20));
    __bf16* qkv    = (__bf16*)(ws + (size_t)(16u << 20));
    __bf16* attn   = (__bf16*)(ws + (size_t)(40u << 20));

    k_cvt<<<4096, 256, 0, stream>>>(x, xb, 4096 * 1024 / 4);
    k_transpose<<<dim3(96, 32), 256, 0, stream>>>(Wqkv, Wqkv_t, 1024, 3072);
    k_transpose<<<dim3(32, 32), 256, 0, stream>>>(Wout, Wout_t, 1024, 1024);
    k_gemm_bt<0><<<dim3(24, 32), 256, 0, stream>>>(xb, Wqkv_t, bqkv, (void*)qkv, 4096, 3072, 1024);
    k_attn<<<dim3(16, 32), 256, 0, stream>>>(qkv, attn);
    k_gemm_bt<1><<<dim3(8, 32), 256, 0, stream>>>(attn, Wout_t, bout, (void*)d_out, 4096, 1024, 1024);
    (void)outp; (void)in_sizes; (void)n_in; (void)out_size; (void)ws_size;
}

// Round 2
// 266.272 us; speedup vs baseline: 1.2570x; 1.2570x over previous
//
#include <hip/hip_runtime.h>
#include <hip/hip_bf16.h>

// SelfAttention: x[2,2048,1024] -> qkv -> 16-head attention -> out proj.
// bf16 MFMA everywhere, fp32 accumulation.

typedef __attribute__((ext_vector_type(8))) __bf16 bf16x8;
typedef __attribute__((ext_vector_type(4))) __bf16 bf16x4;
typedef __attribute__((ext_vector_type(4))) float f32x4;

__device__ __forceinline__ void gload_lds16(const void* g, void* l) {
    __builtin_amdgcn_global_load_lds((const __attribute__((address_space(1))) void*)g,
                                     (__attribute__((address_space(3))) void*)l, 16, 0, 0);
}

// DPP rotate within 16-lane rows (row_ror:N). Reduction over 16 lanes via 8,4,2,1.
template <int CTRL>
__device__ __forceinline__ float rot16(float x) {
    union { float f; int i; } u;
    u.f = x;
    u.i = __builtin_amdgcn_update_dpp(0, u.i, CTRL, 0xF, 0xF, true);
    return u.f;
}
__device__ __forceinline__ float red16_max(float t) {
    t = fmaxf(t, rot16<0x128>(t));
    t = fmaxf(t, rot16<0x124>(t));
    t = fmaxf(t, rot16<0x122>(t));
    t = fmaxf(t, rot16<0x121>(t));
    return t;
}
__device__ __forceinline__ float red16_sum(float t) {
    t += rot16<0x128>(t);
    t += rot16<0x124>(t);
    t += rot16<0x122>(t);
    t += rot16<0x121>(t);
    return t;
}

// ---------------- pre-pass: f32 -> bf16 (vector x4) ----------------
__global__ __launch_bounds__(256) void k_cvt(const float* __restrict__ in,
                                             __bf16* __restrict__ out, int n4) {
    int i = blockIdx.x * 256 + threadIdx.x;
    if (i >= n4) return;
    float4 v = ((const float4*)in)[i];
    bf16x4 r = {(__bf16)v.x, (__bf16)v.y, (__bf16)v.z, (__bf16)v.w};
    ((bf16x4*)out)[i] = r;
}

// ---------------- pre-pass: W [K][N] f32 -> Wt [N][K] bf16 ----------------
__global__ __launch_bounds__(256) void k_transpose(const float* __restrict__ W,
                                                   __bf16* __restrict__ Wt, int K, int N) {
    __shared__ float t[32][33];
    int n0 = blockIdx.x * 32, k0 = blockIdx.y * 32;
    int tx = threadIdx.x & 31, ty = threadIdx.x >> 5;
    for (int j = ty; j < 32; j += 8) t[j][tx] = W[(size_t)(k0 + j) * N + n0 + tx];
    __syncthreads();
    for (int j = ty; j < 32; j += 8)
        Wt[(size_t)(n0 + j) * K + k0 + tx] = (__bf16)t[tx][j];
}

// ---------------- GEMM: C[M][N] = A[M][K] * Bt[N][K]^T + bias ----------------
// 128x128 tile, BK=32, 4 waves each 64x64 (4x4 16x16x32 mfma). m97 structure.
template <int OUTMODE>  // 0: bf16 out, 1: f32 out
__global__ __launch_bounds__(256) void k_gemm_bt(const __bf16* __restrict__ A,
                                                 const __bf16* __restrict__ Bt,
                                                 const float* __restrict__ bias,
                                                 void* __restrict__ Cv, int M, int N, int K) {
    __shared__ __bf16 As[128 * 32];
    __shared__ __bf16 Bs[128 * 32];
    const int tn = blockIdx.x * 128, tm = blockIdx.y * 128;
    const int tid = threadIdx.x, lane = tid & 63, wid = tid >> 6;
    const int wr = wid >> 1, wc = wid & 1;
    const int llo = lane & 15, lhi = lane >> 4;
    f32x4 acc[4][4] = {};
    for (int kk = 0; kk < K; kk += 32) {
        __syncthreads();
#pragma unroll
        for (int j = 0; j < 2; ++j) {
            const int elem = wid * 1024 + j * 512 + lane * 8;
            const int row = elem >> 5, col = elem & 31;
            gload_lds16(A + (size_t)(tm + row) * K + kk + col, (char*)As + 2 * (wid * 1024 + j * 512));
            gload_lds16(Bt + (size_t)(tn + row) * K + kk + col, (char*)Bs + 2 * (wid * 1024 + j * 512));
        }
        __syncthreads();
        bf16x8 af[4], bfr[4];
#pragma unroll
        for (int m = 0; m < 4; ++m)
            af[m] = *(const bf16x8*)(As + (64 * wr + 16 * m + llo) * 32 + 8 * lhi);
#pragma unroll
        for (int n = 0; n < 4; ++n)
            bfr[n] = *(const bf16x8*)(Bs + (64 * wc + 16 * n + llo) * 32 + 8 * lhi);
#pragma unroll
        for (int m = 0; m < 4; ++m)
#pragma unroll
            for (int n = 0; n < 4; ++n)
                acc[m][n] = __builtin_amdgcn_mfma_f32_16x16x32_bf16(af[m], bfr[n], acc[m][n], 0, 0, 0);
    }
    const int row0 = tm + 64 * wr + 4 * lhi, col0 = tn + 64 * wc + llo;
#pragma unroll
    for (int n = 0; n < 4; ++n) {
        const int col = col0 + 16 * n;
        const float bv = bias[col];
#pragma unroll
        for (int m = 0; m < 4; ++m)
#pragma unroll
            for (int r = 0; r < 4; ++r) {
                const int row = row0 + 16 * m + r;
                const float val = acc[m][n][r] + bv;
                if (OUTMODE == 0) ((__bf16*)Cv)[(size_t)row * N + col] = (__bf16)val;
                else ((float*)Cv)[(size_t)row * N + col] = val;
            }
    }
}

// ---------------- flash attention ----------------
// qkv: [4096][3072] bf16 (cols: q=h*64.., k=1024+h*64.., v=2048+h*64..)
// out: [4096][1024] bf16. 512 blocks (XCD-swizzled), 256 threads (4 waves).
// Each wave: 32 q-rows. KT=64 keys/iter. Pipelined K/V staging (T14),
// double-XOR-swizzled V^T tile, DPP softmax reduce, defer-rescale (T13).
__global__ __launch_bounds__(256) void k_attn(const __bf16* __restrict__ qkv,
                                              __bf16* __restrict__ out) {
    constexpr int LDK = 72;           // K/P padded stride
    __shared__ __bf16 Kl[64 * LDK];   // 9216 B
    __shared__ __bf16 Vt[64 * 64];    // V^T, stride 64, double-XOR swizzled; 8192 B
    __shared__ __bf16 Pl[128 * LDK];  // per-wave P tiles; 18432 B
    // XCD-aware decode: 4 bh-slices per XCD (K/V set = 2 MB <= 4 MB L2/XCD).
    const int hwid = blockIdx.x;
    const int xcd = hwid & 7, slot = hwid >> 3;
    const int bh = xcd * 4 + (slot >> 4), qt = slot & 15;
    const int b = bh >> 4, h = bh & 15;
    const size_t rowbase = (size_t)b * 2048;
    const int tid = threadIdx.x, lane = tid & 63, wid = tid >> 6;
    const int llo = lane & 15, lhi = lane >> 4;

    // Q fragments: direct global->reg (one-time, L2-resident)
    bf16x8 qf[2][2];
#pragma unroll
    for (int m = 0; m < 2; ++m)
#pragma unroll
        for (int ks = 0; ks < 2; ++ks)
            qf[m][ks] = *(const bf16x8*)(qkv + (rowbase + (size_t)qt * 128 + 32 * wid + 16 * m + llo) * 3072 + h * 64 + 32 * ks + 8 * lhi);

    float mrun[2][4], lrun[2][4];
    f32x4 acco[2][4] = {};
#pragma unroll
    for (int m = 0; m < 2; ++m)
#pragma unroll
        for (int r = 0; r < 4; ++r) { mrun[m][r] = -1e30f; lrun[m][r] = 0.f; }

    __bf16* Pw = Pl + wid * 32 * LDK;
    constexpr float SC = 0.18033688011112042f;  // (1/8) * log2(e)

    // staging indices: idx over 512 = 64 keys x 8 dk-vecs; 2 vecs each of K,V per thread
    const int key0 = tid >> 3, key1 = (256 + tid) >> 3;
    const int dk0 = (tid & 7) * 8;  // same for both halves

    // prologue: load kt=0 into regs
    bf16x8 kreg[2], vreg[2];
    {
        const size_t g0 = (rowbase + key0) * 3072 + h * 64 + dk0;
        const size_t g1 = (rowbase + key1) * 3072 + h * 64 + dk0;
        kreg[0] = *(const bf16x8*)(qkv + g0 + 1024);
        vreg[0] = *(const bf16x8*)(qkv + g0 + 2048);
        kreg[1] = *(const bf16x8*)(qkv + g1 + 1024);
        vreg[1] = *(const bf16x8*)(qkv + g1 + 2048);
    }

    for (int kt = 0; kt < 32; ++kt) {
        __syncthreads();  // previous tile's readers done
        // write staged regs -> LDS
#pragma unroll
        for (int it = 0; it < 2; ++it) {
            const int key = it ? key1 : key0;
            *(bf16x8*)(Kl + key * LDK + dk0) = kreg[it];
#pragma unroll
            for (int j = 0; j < 8; ++j) {
                const int dk = dk0 + j;
                const int xi = (dk & 7) ^ ((dk >> 3) & 7);
                Vt[dk * 64 + (key ^ (xi << 3))] = vreg[it][j];
            }
        }
        __syncthreads();
        // issue next-tile loads (latency hides under compute below)
        {
            const int ktn = kt + 1 < 32 ? kt + 1 : 31;
            const size_t g0 = (rowbase + (size_t)ktn * 64 + key0) * 3072 + h * 64 + dk0;
            const size_t g1 = (rowbase + (size_t)ktn * 64 + key1) * 3072 + h * 64 + dk0;
            kreg[0] = *(const bf16x8*)(qkv + g0 + 1024);
            vreg[0] = *(const bf16x8*)(qkv + g0 + 2048);
            kreg[1] = *(const bf16x8*)(qkv + g1 + 1024);
            vreg[1] = *(const bf16x8*)(qkv + g1 + 2048);
        }
        // S = Q K^T (raw scores; 1/8 folded into exp2 scale)
        f32x4 sf[2][4] = {};
        __builtin_amdgcn_s_setprio(1);
#pragma unroll
        for (int ks = 0; ks < 2; ++ks)
#pragma unroll
            for (int n = 0; n < 4; ++n) {
                const bf16x8 bfr = *(const bf16x8*)(Kl + (n * 16 + llo) * LDK + 32 * ks + 8 * lhi);
#pragma unroll
                for (int m = 0; m < 2; ++m)
                    sf[m][n] = __builtin_amdgcn_mfma_f32_16x16x32_bf16(qf[m][ks], bfr, sf[m][n], 0, 0, 0);
            }
        __builtin_amdgcn_s_setprio(0);
        // online softmax: DPP 16-lane reduce, defer-rescale (raw thr 32 -> p <= 2^5.8)
#pragma unroll
        for (int m = 0; m < 2; ++m)
#pragma unroll
            for (int r = 0; r < 4; ++r) {
                float t = fmaxf(fmaxf(sf[m][0][r], sf[m][1][r]), fmaxf(sf[m][2][r], sf[m][3][r]));
                t = red16_max(t);
                if (t > mrun[m][r] + 32.0f) {
                    const float corr = exp2f((mrun[m][r] - t) * SC);
                    mrun[m][r] = t;
                    lrun[m][r] *= corr;
#pragma unroll
                    for (int n = 0; n < 4; ++n) acco[m][n][r] *= corr;
                }
                const float mm = mrun[m][r];
                float rs = 0.f;
#pragma unroll
                for (int n = 0; n < 4; ++n) {
                    const float p = exp2f((sf[m][n][r] - mm) * SC);
                    sf[m][n][r] = p;
                    rs += p;
                }
                lrun[m][r] += red16_sum(rs);
            }
        // P -> wave-private LDS (in-order per wave; no barrier needed)
#pragma unroll
        for (int m = 0; m < 2; ++m)
#pragma unroll
            for (int n = 0; n < 4; ++n)
#pragma unroll
                for (int r = 0; r < 4; ++r)
                    Pw[(16 * m + 4 * lhi + r) * LDK + n * 16 + llo] = (__bf16)sf[m][n][r];
        // O += P @ V
        __builtin_amdgcn_s_setprio(1);
#pragma unroll
        for (int ks = 0; ks < 2; ++ks) {
            bf16x8 pa[2];
#pragma unroll
            for (int m = 0; m < 2; ++m)
                pa[m] = *(const bf16x8*)(Pw + (16 * m + llo) * LDK + 32 * ks + 8 * lhi);
#pragma unroll
            for (int n = 0; n < 4; ++n) {
                const int dk = n * 16 + llo;
                const int xi = (dk & 7) ^ ((dk >> 3) & 7);
                const bf16x8 bfr = *(const bf16x8*)(Vt + dk * 64 + ((32 * ks + 8 * lhi) ^ (xi << 3)));
#pragma unroll
                for (int m = 0; m < 2; ++m)
                    acco[m][n] = __builtin_amdgcn_mfma_f32_16x16x32_bf16(pa[m], bfr, acco[m][n], 0, 0, 0);
            }
        }
        __builtin_amdgcn_s_setprio(0);
    }
    // epilogue: normalize, write [4096][1024] bf16
#pragma unroll
    for (int m = 0; m < 2; ++m)
#pragma unroll
        for (int r = 0; r < 4; ++r) {
            const float inv = 1.f / lrun[m][r];
            const size_t row = rowbase + (size_t)qt * 128 + 32 * wid + 16 * m + 4 * lhi + r;
#pragma unroll
            for (int n = 0; n < 4; ++n)
                out[row * 1024 + h * 64 + n * 16 + llo] = (__bf16)(acco[m][n][r] * inv);
        }
}

extern "C" void kernel_launch(void* const* d_in, const int* in_sizes, int n_in,
                              void* d_out, int out_size, void* d_ws, size_t ws_size,
                              hipStream_t stream) {
    const float* x    = (const float*)d_in[0];
    const float* Wqkv = (const float*)d_in[1];
    const float* bqkv = (const float*)d_in[2];
    const float* Wout = (const float*)d_in[3];
    const float* bout = (const float*)d_in[4];
    char* ws = (char*)d_ws;
    // workspace layout (bytes): xb 8MB | Wqkv_t 6MB | Wout_t 2MB | qkv 24MB | attn 8MB
    __bf16* xb     = (__bf16*)(ws);
    __bf16* Wqkv_t = (__bf16*)(ws + (size_t)(8u << 20));
    __bf16* Wout_t = (__bf16*)(ws + (size_t)(14u << 20));
    __bf16* qkv    = (__bf16*)(ws + (size_t)(16u << 20));
    __bf16* attn   = (__bf16*)(ws + (size_t)(40u << 20));

    k_cvt<<<4096, 256, 0, stream>>>(x, xb, 4096 * 1024 / 4);
    k_transpose<<<dim3(96, 32), 256, 0, stream>>>(Wqkv, Wqkv_t, 1024, 3072);
    k_transpose<<<dim3(32, 32), 256, 0, stream>>>(Wout, Wout_t, 1024, 1024);
    k_gemm_bt<0><<<dim3(24, 32), 256, 0, stream>>>(xb, Wqkv_t, bqkv, (void*)qkv, 4096, 3072, 1024);
    k_attn<<<512, 256, 0, stream>>>(qkv, attn);
    k_gemm_bt<1><<<dim3(8, 32), 256, 0, stream>>>(attn, Wout_t, bout, (void*)d_out, 4096, 1024, 1024);
    (void)in_sizes; (void)n_in; (void)out_size; (void)ws_size;
}